// Round 5
// baseline (9546.140 us; speedup 1.0000x reference)
//
#include <hip/hip_runtime.h>
#include <math.h>

namespace {

constexpr int kB  = 256;   // batch
constexpr int kT  = 512;   // timesteps
constexpr int kIn = 128;   // layer0 input size
constexpr int kH  = 256;   // hidden
constexpr int kG  = 1024;  // 4*H
constexpr int kNC = 100;   // classes
constexpr int kCT = 64;    // timestep chunk
constexpr int kNCh = kT / kCT;

typedef __bf16 bf16x8 __attribute__((ext_vector_type(8)));
typedef float f32x4 __attribute__((ext_vector_type(4)));
static_assert(sizeof(bf16x8) == 16, "bf16x8 must be 4 VGPRs");

__device__ __forceinline__ float sigm(float x) {
  return __builtin_amdgcn_rcpf(1.0f + __expf(-x));
}
__device__ __forceinline__ float tanh_f(float x) {
  const float e = __expf(-2.0f * x);
  return (1.0f - e) * __builtin_amdgcn_rcpf(1.0f + e);
}
__device__ __forceinline__ unsigned short f2bf(float f) {
  return __builtin_bit_cast(unsigned short, (__bf16)f);
}

// Async global->LDS, 16B per lane. Dest is wave-uniform base; HW adds lane*16.
__device__ __forceinline__ void glds16(const void* g, void* l) {
  __builtin_amdgcn_global_load_lds(
      (const __attribute__((address_space(1))) void*)g,
      (__attribute__((address_space(3))) void*)l, 16, 0, 0);
}

// ---------------------------------------------------------------------------
// Pack W_hh [4H][H] fp32 into bf16 MFMA B-fragment order:
//   flat = ((((wv*4+g)*8)+kb)*64 + l)*8 + e
//   B[k][n] = Whh[n][k], n = g*256 + wv*16 + (l&15), k = kb*32 + ((l>>4)&3)*8 + e
__global__ __launch_bounds__(256) void pack_whh_frag(
    const float* __restrict__ whh, unsigned short* __restrict__ wpk) {
  const int idx = blockIdx.x * 256 + threadIdx.x;   // 0..262143
  const int e  = idx & 7;
  const int l  = (idx >> 3) & 63;
  const int kb = (idx >> 9) & 7;
  const int g  = (idx >> 12) & 3;
  const int wv = idx >> 14;
  const int n = (g << 8) | (wv << 4) | (l & 15);
  const int k = (kb << 5) | (((l >> 4) & 3) << 3) | e;
  wpk[idx] = f2bf(whh[n * kH + k]);
}

// ---------------------------------------------------------------------------
// MFMA LSTM recurrence, half-resident + LDS-ring streamed weights, and
// P in recurrence-native layout P2 so each wave loads its step-P as
// 4 fully-coalesced dwordx4 (1KB/instr) instead of 256 scalar loads/CU.
// P2 flat index: (((bblk*64 + tt)*16 + wv)*4 + g)*256 + unit*16 + brow
//   (bblk = b>>4, brow = b&15, unit = jj&15)
__global__ __launch_bounds__(1024, 4) void lstm_rec_mfma(
    const float* __restrict__ P2,           // permuted projections
    const unsigned short* __restrict__ wpk, // packed bf16 B-fragments
    float* __restrict__ hstate,             // [kB][kH]
    float* __restrict__ cstate,             // [kB][kH]
    float* __restrict__ Hout,               // [kB*kCT][kH] or nullptr
    int first) {
  const int tid = threadIdx.x;
  const int wv = tid >> 6;
  const int l  = tid & 63;
  const int b0 = blockIdx.x << 4;
  const int jj = (wv << 4) | (l & 15);   // hidden unit owned (D column)
  const int mg = (l >> 4) << 2;          // base batch row of this lane's D rows

  __shared__ __align__(16) unsigned short ring[4][16384];  // 4 x 32KB
  __shared__ __align__(16) unsigned short abuf[2][4096];   // 2 x 8KB

  // ---- resident B-fragments: gates 0,1 (64 VGPRs) ----
  bf16x8 wr[2][8];
#pragma unroll
  for (int g = 0; g < 2; ++g)
#pragma unroll
    for (int kb = 0; kb < 8; ++kb)
      wr[g][kb] = *reinterpret_cast<const bf16x8*>(
          wpk + (size_t)(((wv * 4 + g) * 8 + kb) * 64 + l) * 8);

  // ---- state load / init; publish h into abuf[0] in fragment order ----
  f32x4 c4;
  float hnew[4];
  if (first) {
#pragma unroll
    for (int r = 0; r < 4; ++r) { c4[r] = 0.f; hnew[r] = 0.f; }
  } else {
#pragma unroll
    for (int r = 0; r < 4; ++r) {
      hnew[r] = hstate[(b0 + mg + r) * kH + jj];
      c4[r]   = cstate[(b0 + mg + r) * kH + jj];
    }
  }
  const int kb_w = jj >> 5, hi_w = (jj >> 3) & 3, e_w = jj & 7;
#pragma unroll
  for (int r = 0; r < 4; ++r)
    abuf[0][kb_w * 512 + ((mg + r) | (hi_w << 4)) * 8 + e_w] = f2bf(hnew[r]);

  // ---- prime ring slices 0..3 into slots 0..3 ----
#pragma unroll
  for (int kb = 0; kb < 4; ++kb) {
    glds16(wpk + (size_t)(((wv * 4 + 2) * 8 + kb) * 64 + l) * 8,
           &ring[kb][(wv * 2 + 0) * 512]);
    glds16(wpk + (size_t)(((wv * 4 + 3) * 8 + kb) * 64 + l) * 8,
           &ring[kb][(wv * 2 + 1) * 512]);
  }

  // ---- P2 base for this lane; step tt at +tt*16384, gate g at +g*256 ----
  const float* __restrict__ Pb =
      P2 + (((size_t)blockIdx.x * 64 * 16 + wv) << 10) + ((l & 15) << 4) + mg;

  // ---- P prefetch for step 0: 4 coalesced dwordx4 per wave ----
  f32x4 pfr[4];
#pragma unroll
  for (int g = 0; g < 4; ++g)
    pfr[g] = *reinterpret_cast<const f32x4*>(Pb + (g << 8));

  __syncthreads();  // vmcnt(0) drain: ring slots 0..3 + pfr valid

  for (int tt = 0; tt < kCT; ++tt) {
    f32x4 acc[4];
#pragma unroll
    for (int g = 0; g < 4; ++g) acc[g] = pfr[g];

    // prefetch next step's P (full MFMA loop + activation of latency cover)
    const int tn = (tt + 1 < kCT) ? (tt + 1) : tt;
#pragma unroll
    for (int g = 0; g < 4; ++g)
      pfr[g] = *reinterpret_cast<const f32x4*>(Pb + (size_t)tn * 16384 + (g << 8));

    const unsigned short* __restrict__ ab = abuf[tt & 1];

#pragma unroll
    for (int kb = 0; kb < 8; ++kb) {
      if (kb >= 4) asm volatile("s_waitcnt vmcnt(6)" ::: "memory");
      const unsigned short* sl = ring[kb & 3];
      const bf16x8 s2 = *reinterpret_cast<const bf16x8*>(sl + (wv * 2 + 0) * 512 + l * 8);
      const bf16x8 s3 = *reinterpret_cast<const bf16x8*>(sl + (wv * 2 + 1) * 512 + l * 8);
      const bf16x8 a  = *reinterpret_cast<const bf16x8*>(ab + kb * 512 + l * 8);
      acc[0] = __builtin_amdgcn_mfma_f32_16x16x32_bf16(a, wr[0][kb], acc[0], 0, 0, 0);
      acc[1] = __builtin_amdgcn_mfma_f32_16x16x32_bf16(a, wr[1][kb], acc[1], 0, 0, 0);
      acc[2] = __builtin_amdgcn_mfma_f32_16x16x32_bf16(a, s2, acc[2], 0, 0, 0);
      acc[3] = __builtin_amdgcn_mfma_f32_16x16x32_bf16(a, s3, acc[3], 0, 0, 0);
      // rolling refill: slot kb%4 <- slice (kb+4)%8 (next use 4 iters away)
      const int nk = (kb + 4) & 7;
      glds16(wpk + (size_t)(((wv * 4 + 2) * 8 + nk) * 64 + l) * 8,
             &ring[kb & 3][(wv * 2 + 0) * 512]);
      glds16(wpk + (size_t)(((wv * 4 + 3) * 8 + nk) * 64 + l) * 8,
             &ring[kb & 3][(wv * 2 + 1) * 512]);
    }

    // ---- in-lane activation: lane holds i,f,g,o for rows mg..mg+3, unit jj
#pragma unroll
    for (int r = 0; r < 4; ++r) {
      const float ig = sigm(acc[0][r]);
      const float fg = sigm(acc[1][r]);
      const float gg = tanh_f(acc[2][r]);
      const float og = sigm(acc[3][r]);
      const float cc = fg * c4[r] + ig * gg;
      c4[r] = cc;
      hnew[r] = og * tanh_f(cc);
    }

    if (Hout) {
#pragma unroll
      for (int r = 0; r < 4; ++r)
        Hout[((size_t)(b0 + mg + r) * kCT + tt) * kH + jj] = hnew[r];
    }
    // ---- publish new h (bf16) into the other buffer, fragment order ----
    unsigned short* an = abuf[(tt + 1) & 1];
#pragma unroll
    for (int r = 0; r < 4; ++r)
      an[kb_w * 512 + ((mg + r) | (hi_w << 4)) * 8 + e_w] = f2bf(hnew[r]);
    __syncthreads();  // drains glds refills + pfr (vmcnt(0))
  }

#pragma unroll
  for (int r = 0; r < 4; ++r) {
    hstate[(b0 + mg + r) * kH + jj] = hnew[r];
    cstate[(b0 + mg + r) * kH + jj] = c4[r];
  }
}

// ---------------------------------------------------------------------------
// GEMM: acc[m][n] = sum_k X[xrow(m)][k] * W[n][k] + b1[n] + b2[n]
// Epilogue writes into the recurrence-native P2 layout (see lstm_rec_mfma).
template <int K>
__global__ __launch_bounds__(256) void gemm_xw(
    const float* __restrict__ X, const float* __restrict__ W,
    const float* __restrict__ b1, const float* __restrict__ b2,
    float* __restrict__ P2, int t0, int xT) {
  __shared__ float sA[64][20];
  __shared__ float sB[64][20];
  const int tid = threadIdx.x;
  const int tx = tid & 15;
  const int ty = tid >> 4;
  const int lm = tid >> 2;
  const int lk = (tid & 3) << 2;
  const int mt = blockIdx.y;
  const int nt = blockIdx.x;

  const int m_g = mt * 64 + lm;
  const int xrow = (m_g >> 6) * xT + t0 + (m_g & 63);
  const float* Arow = X + (size_t)xrow * K;
  const float* Brow = W + (size_t)(nt * 64 + lm) * K;

  float acc[4][4] = {};
  for (int kt = 0; kt < K; kt += 16) {
    const float4 av = *reinterpret_cast<const float4*>(Arow + kt + lk);
    const float4 bv = *reinterpret_cast<const float4*>(Brow + kt + lk);
    __syncthreads();
    *reinterpret_cast<float4*>(&sA[lm][lk]) = av;
    *reinterpret_cast<float4*>(&sB[lm][lk]) = bv;
    __syncthreads();
#pragma unroll
    for (int kq = 0; kq < 4; ++kq) {
      float4 a4[4], b4[4];
#pragma unroll
      for (int i = 0; i < 4; ++i)
        a4[i] = *reinterpret_cast<const float4*>(&sA[ty + 16 * i][kq * 4]);
#pragma unroll
      for (int j = 0; j < 4; ++j)
        b4[j] = *reinterpret_cast<const float4*>(&sB[tx + 16 * j][kq * 4]);
#pragma unroll
      for (int i = 0; i < 4; ++i)
#pragma unroll
        for (int j = 0; j < 4; ++j) {
          acc[i][j] += a4[i].x * b4[j].x;
          acc[i][j] += a4[i].y * b4[j].y;
          acc[i][j] += a4[i].z * b4[j].z;
          acc[i][j] += a4[i].w * b4[j].w;
        }
    }
  }
#pragma unroll
  for (int j = 0; j < 4; ++j) {
    const int n = nt * 64 + tx + 16 * j;
    const float bb = b1[n] + b2[n];
    const int g = n >> 8, wvv = (n >> 4) & 15, u = n & 15;
#pragma unroll
    for (int i = 0; i < 4; ++i) {
      const int m = mt * 64 + ty + 16 * i;
      const int b = m >> 6, tt = m & 63;          // kCT == 64
      const int bblk = b >> 4, brow = b & 15;
      const size_t idx =
          ((((size_t)(bblk * 64 + tt) * 16 + wvv) * 4 + g) << 8) +
          (u << 4) + brow;
      P2[idx] = acc[i][j] + bb;
    }
  }
}

// out[b][n] = sum_k hlast[b][k] * fcw[n][k] + fcb[n]
__global__ __launch_bounds__(128) void fc_kernel(
    const float* __restrict__ hlast, const float* __restrict__ fcw,
    const float* __restrict__ fcb, float* __restrict__ out) {
  const int b = blockIdx.x;
  const int n = threadIdx.x;
  __shared__ float sh[kH];
  sh[n] = hlast[b * kH + n];
  sh[n + 128] = hlast[b * kH + n + 128];
  __syncthreads();
  if (n < kNC) {
    float a = fcb[n];
    const float* wrow = fcw + n * kH;
#pragma unroll 8
    for (int k = 0; k < kH; ++k) a += sh[k] * wrow[k];
    out[b * kNC + n] = a;
  }
}

}  // namespace

extern "C" void kernel_launch(void* const* d_in, const int* in_sizes, int n_in,
                              void* d_out, int out_size, void* d_ws, size_t ws_size,
                              hipStream_t stream) {
  (void)in_sizes; (void)n_in; (void)out_size; (void)ws_size;
  const float* x    = (const float*)d_in[0];
  const float* Wih0 = (const float*)d_in[1];
  const float* Whh0 = (const float*)d_in[2];
  const float* bih0 = (const float*)d_in[3];
  const float* bhh0 = (const float*)d_in[4];
  const float* Wih1 = (const float*)d_in[5];
  const float* Whh1 = (const float*)d_in[6];
  const float* bih1 = (const float*)d_in[7];
  const float* bhh1 = (const float*)d_in[8];
  const float* fcw  = (const float*)d_in[9];
  const float* fcb  = (const float*)d_in[10];
  float* out = (float*)d_out;

  // Workspace layout (~146 MB)
  char* base = (char*)d_ws;
  const size_t szP = (size_t)kB * kCT * kG * sizeof(float);  // 64 MB
  const size_t szH = (size_t)kB * kCT * kH * sizeof(float);  // 16 MB
  const size_t szS = (size_t)kB * kH * sizeof(float);        // 256 KB
  const size_t szW = (size_t)262144 * sizeof(unsigned short);// 512 KB
  float* P0  = (float*)(base);
  float* P1  = (float*)(base + szP);
  float* H0  = (float*)(base + 2 * szP);
  float* h0s = (float*)(base + 2 * szP + szH);
  float* c0s = (float*)(base + 2 * szP + szH + 1 * szS);
  float* h1s = (float*)(base + 2 * szP + szH + 2 * szS);
  float* c1s = (float*)(base + 2 * szP + szH + 3 * szS);
  unsigned short* Wpk0 = (unsigned short*)(base + 2 * szP + szH + 4 * szS);
  unsigned short* Wpk1 = (unsigned short*)(base + 2 * szP + szH + 4 * szS + szW);

  pack_whh_frag<<<dim3(1024), dim3(256), 0, stream>>>(Whh0, Wpk0);
  pack_whh_frag<<<dim3(1024), dim3(256), 0, stream>>>(Whh1, Wpk1);

  const dim3 ggrid(kG / 64, kB * kCT / 64);  // (16, 256)
  for (int ch = 0; ch < kNCh; ++ch) {
    const int first = (ch == 0) ? 1 : 0;
    gemm_xw<kIn><<<ggrid, dim3(256), 0, stream>>>(x, Wih0, bih0, bhh0, P0,
                                                  ch * kCT, kT);
    lstm_rec_mfma<<<dim3(kB / 16), dim3(1024), 0, stream>>>(P0, Wpk0, h0s, c0s,
                                                            H0, first);
    gemm_xw<kH><<<ggrid, dim3(256), 0, stream>>>(H0, Wih1, bih1, bhh1, P1,
                                                 0, kCT);
    lstm_rec_mfma<<<dim3(kB / 16), dim3(1024), 0, stream>>>(P1, Wpk1, h1s, c1s,
                                                            nullptr, first);
  }
  fc_kernel<<<dim3(kB), dim3(128), 0, stream>>>(h1s, fcw, fcb, out);
}

// Round 6
// 5817.284 us; speedup vs baseline: 1.6410x; 1.6410x over previous
//
#include <hip/hip_runtime.h>
#include <math.h>

namespace {

constexpr int kB  = 256;   // batch
constexpr int kT  = 512;   // timesteps
constexpr int kIn = 128;   // layer0 input size
constexpr int kH  = 256;   // hidden
constexpr int kG  = 1024;  // 4*H
constexpr int kNC = 100;   // classes
constexpr int kCT = 64;    // timestep chunk
constexpr int kNCh = kT / kCT;
constexpr int kNS = 4;     // hidden slices (blocks per batch-group)
constexpr int kCntStride = 72;            // ints per (bblk) counter row
constexpr int kCntSlot = 8 * kCntStride;  // ints per dispatch slot

typedef __bf16 bf16x8 __attribute__((ext_vector_type(8)));
typedef float f32x4 __attribute__((ext_vector_type(4)));
static_assert(sizeof(bf16x8) == 16, "bf16x8 must be 4 VGPRs");

__device__ __forceinline__ float sigm(float x) {
  return __builtin_amdgcn_rcpf(1.0f + __expf(-x));
}
__device__ __forceinline__ float tanh_f(float x) {
  const float e = __expf(-2.0f * x);
  return (1.0f - e) * __builtin_amdgcn_rcpf(1.0f + e);
}
__device__ __forceinline__ unsigned short f2bf(float f) {
  return __builtin_bit_cast(unsigned short, (__bf16)f);
}

// Async global->LDS, 16B per lane. Dest is wave-uniform base; HW adds lane*16.
__device__ __forceinline__ void glds16(const void* g, void* l) {
  __builtin_amdgcn_global_load_lds(
      (const __attribute__((address_space(1))) void*)g,
      (__attribute__((address_space(3))) void*)l, 16, 0, 0);
}

// ---------------------------------------------------------------------------
// Pack W_hh [4H][H] fp32 into bf16 MFMA B-fragment order:
//   flat = ((((wv16*4+g)*8)+kb)*64 + l)*8 + e
//   B[k][n] = Whh[n][k], n = g*256 + wv16*16 + (l&15), k = kb*32 + ((l>>4)&3)*8 + e
__global__ __launch_bounds__(256) void pack_whh_frag(
    const float* __restrict__ whh, unsigned short* __restrict__ wpk) {
  const int idx = blockIdx.x * 256 + threadIdx.x;   // 0..262143
  const int e  = idx & 7;
  const int l  = (idx >> 3) & 63;
  const int kb = (idx >> 9) & 7;
  const int g  = (idx >> 12) & 3;
  const int wv = idx >> 14;
  const int n = (g << 8) | (wv << 4) | (l & 15);
  const int k = (kb << 5) | (((l >> 4) & 3) << 3) | e;
  wpk[idx] = f2bf(whh[n * kH + k]);
}

// ---------------------------------------------------------------------------
// Hidden-partitioned LSTM recurrence. Grid: 32 blocks = 8 batch-groups(32 rows)
// x 4 hidden-slices(64 units). Block: 512 thr = 8 waves (2/SIMD). Wave (mi,ug)
// owns m-tile mi (16 rows) x 16 units x all 4 gates -> W-slice fully VGPR-
// resident (128 regs/lane), in-lane activation, c private to the block.
// Per step: blocks exchange h slices via global hx (bf16, double-buffered),
// synced per batch-group with agent-scope counters (cross-XCD safe). h for the
// next step is pulled with global_load_lds into fragment-order LDS.
__global__ __launch_bounds__(512, 2) void lstm_rec_coop(
    const float* __restrict__ P2,           // permuted projections (see gemm)
    const unsigned short* __restrict__ wpk, // packed bf16 B-fragments
    float* __restrict__ cstate,             // [kB][kH] fp32, block-exclusive
    float* __restrict__ Hout,               // [kB*kCT][kH] fp32 or null
    float* __restrict__ hlast,              // [kB][kH] fp32 or null
    unsigned short* __restrict__ hx,        // [2][kB][kH] bf16 exchange
    int* __restrict__ cnt,                  // [8][kCntStride], zeroed
    int first) {
  const int tid = threadIdx.x;
  const int wv = tid >> 6;          // 0..7
  const int l  = tid & 63;
  const int mi = wv >> 2;           // m-tile (16 rows)
  const int ug = wv & 3;            // unit group (16 units)
  const int bblk = blockIdx.x >> 2; // batch group (32 rows)
  const int hs   = blockIdx.x & 3;  // hidden slice (64 units)
  const int R0 = bblk << 5;
  const int wv16 = (hs << 2) | ug;                  // 0..15, matches pack/P2
  const int jj = (wv16 << 4) | (l & 15);            // owned hidden unit
  const int mg = (l >> 4) << 2;                     // row offset in m-tile
  const int rowb = R0 + (mi << 4) + mg;             // first of 4 owned rows

  __shared__ __align__(16) unsigned short albuf[2][8][512];  // 16KB A-frags

  int* cntb = cnt + bblk * kCntStride;
  unsigned short* hx0 = hx;
  unsigned short* hx1 = hx + (size_t)kB * kH;

  // ---- resident B-fragments: 4 gates x 8 kb = 128 VGPRs (32KB contiguous) --
  bf16x8 wr[4][8];
#pragma unroll
  for (int g = 0; g < 4; ++g)
#pragma unroll
    for (int kb = 0; kb < 8; ++kb)
      wr[g][kb] = *reinterpret_cast<const bf16x8*>(
          wpk + (size_t)(((wv16 * 4 + g) * 8 + kb) * 64 + l) * 8);

  // ---- c state ----
  f32x4 c4;
  float hnew[4];
  if (first) {
#pragma unroll
    for (int r = 0; r < 4; ++r) c4[r] = 0.f;
  } else {
#pragma unroll
    for (int r = 0; r < 4; ++r) c4[r] = cstate[(rowb + r) * kH + jj];
  }

  // ---- P2 base: step stride 16384 floats, gate stride 256 ----
  const float* __restrict__ Pb =
      P2 + ((size_t)((bblk * 2 + mi) * 64) * 16 + wv16) * 1024 +
      ((l & 15) << 4) + mg;
  f32x4 pfr[4];
#pragma unroll
  for (int g = 0; g < 4; ++g)
    pfr[g] = *reinterpret_cast<const f32x4*>(Pb + (g << 8));

  // ---- glds of A-frags: wave wv pulls frags (gmi, gkb..gkb+1) ----
  const int gmi = wv >> 2;
  const int gkb = (wv & 3) << 1;
  const int grow = R0 + (gmi << 4) + (l & 15);
  const int gcol0 = ((l >> 4) & 3) << 3;
#define ISSUE_GLDS(buf)                                                     \
  {                                                                         \
    _Pragma("unroll") for (int q = 0; q < 2; ++q) {                         \
      const int kb = gkb + q;                                               \
      glds16((buf) + ((size_t)grow << 8) + (kb << 5) + gcol0,               \
             &albuf[gmi][kb][0]);                                           \
    }                                                                       \
  }

  ISSUE_GLDS(hx0);  // step-0 input (zeros or previous chunk's h)

  for (int tt = 0; tt < kCT; ++tt) {
    __syncthreads();  // [A] drains glds (vmcnt0): albuf valid for all waves

    f32x4 acc[4];
#pragma unroll
    for (int g = 0; g < 4; ++g) acc[g] = pfr[g];

    bf16x8 a_cur = *reinterpret_cast<const bf16x8*>(&albuf[mi][0][l * 8]);
#pragma unroll
    for (int kb = 0; kb < 8; ++kb) {
      bf16x8 a_nxt = a_cur;
      if (kb < 7)
        a_nxt = *reinterpret_cast<const bf16x8*>(&albuf[mi][kb + 1][l * 8]);
      acc[0] = __builtin_amdgcn_mfma_f32_16x16x32_bf16(a_cur, wr[0][kb], acc[0], 0, 0, 0);
      acc[1] = __builtin_amdgcn_mfma_f32_16x16x32_bf16(a_cur, wr[1][kb], acc[1], 0, 0, 0);
      acc[2] = __builtin_amdgcn_mfma_f32_16x16x32_bf16(a_cur, wr[2][kb], acc[2], 0, 0, 0);
      acc[3] = __builtin_amdgcn_mfma_f32_16x16x32_bf16(a_cur, wr[3][kb], acc[3], 0, 0, 0);
      a_cur = a_nxt;
    }

    // prefetch next step's P (latency hidden under act + sync)
    if (tt + 1 < kCT) {
#pragma unroll
      for (int g = 0; g < 4; ++g)
        pfr[g] = *reinterpret_cast<const f32x4*>(
            Pb + (size_t)(tt + 1) * 16384 + (g << 8));
    }

    // ---- in-lane activation ----
#pragma unroll
    for (int r = 0; r < 4; ++r) {
      const float ig = sigm(acc[0][r]);
      const float fg = sigm(acc[1][r]);
      const float gg = tanh_f(acc[2][r]);
      const float og = sigm(acc[3][r]);
      const float cc = fg * c4[r] + ig * gg;
      c4[r] = cc;
      hnew[r] = og * tanh_f(cc);
    }

    // ---- publish h slice (bf16) to the other exchange buffer ----
    unsigned short* hw = ((tt + 1) & 1) ? hx1 : hx0;
#pragma unroll
    for (int r = 0; r < 4; ++r)
      hw[((size_t)(rowb + r) << 8) + jj] = f2bf(hnew[r]);
    if (Hout) {
#pragma unroll
      for (int r = 0; r < 4; ++r)
        Hout[((size_t)(rowb + r) * kCT + tt) * kH + jj] = hnew[r];
    }
    if (hlast && tt == kCT - 1) {
#pragma unroll
      for (int r = 0; r < 4; ++r)
        hlast[(rowb + r) * kH + jj] = hnew[r];
    }

    __syncthreads();  // [B] all ds_reads done + all h stores vmcnt-drained

    if (tt + 1 < kCT) {
      if (tid == 0) {
        __builtin_amdgcn_fence(__ATOMIC_RELEASE, "agent");
        __hip_atomic_fetch_add(&cntb[tt + 1], 1, __ATOMIC_RELAXED,
                               __HIP_MEMORY_SCOPE_AGENT);
        while (__hip_atomic_load(&cntb[tt + 1], __ATOMIC_RELAXED,
                                 __HIP_MEMORY_SCOPE_AGENT) < kNS)
          __builtin_amdgcn_s_sleep(1);
        __builtin_amdgcn_fence(__ATOMIC_ACQUIRE, "agent");
      }
      __syncthreads();  // [C] acquire visible to all waves before reads
      unsigned short* hr = ((tt + 1) & 1) ? hx1 : hx0;
      ISSUE_GLDS(hr);
    }
  }
#undef ISSUE_GLDS

#pragma unroll
  for (int r = 0; r < 4; ++r) cstate[(rowb + r) * kH + jj] = c4[r];
}

// ---------------------------------------------------------------------------
// GEMM: acc[m][n] = sum_k X[xrow(m)][k] * W[n][k] + b1[n] + b2[n]
// Epilogue writes the recurrence-native P2 layout:
//   idx = (((bblk16*64+tt)*16 + wv16)*4 + g)*256 + u*16 + brow
template <int K>
__global__ __launch_bounds__(256) void gemm_xw(
    const float* __restrict__ X, const float* __restrict__ W,
    const float* __restrict__ b1, const float* __restrict__ b2,
    float* __restrict__ P2, int t0, int xT) {
  __shared__ float sA[64][20];
  __shared__ float sB[64][20];
  const int tid = threadIdx.x;
  const int tx = tid & 15;
  const int ty = tid >> 4;
  const int lm = tid >> 2;
  const int lk = (tid & 3) << 2;
  const int mt = blockIdx.y;
  const int nt = blockIdx.x;

  const int m_g = mt * 64 + lm;
  const int xrow = (m_g >> 6) * xT + t0 + (m_g & 63);
  const float* Arow = X + (size_t)xrow * K;
  const float* Brow = W + (size_t)(nt * 64 + lm) * K;

  float acc[4][4] = {};
  for (int kt = 0; kt < K; kt += 16) {
    const float4 av = *reinterpret_cast<const float4*>(Arow + kt + lk);
    const float4 bv = *reinterpret_cast<const float4*>(Brow + kt + lk);
    __syncthreads();
    *reinterpret_cast<float4*>(&sA[lm][lk]) = av;
    *reinterpret_cast<float4*>(&sB[lm][lk]) = bv;
    __syncthreads();
#pragma unroll
    for (int kq = 0; kq < 4; ++kq) {
      float4 a4[4], b4[4];
#pragma unroll
      for (int i = 0; i < 4; ++i)
        a4[i] = *reinterpret_cast<const float4*>(&sA[ty + 16 * i][kq * 4]);
#pragma unroll
      for (int j = 0; j < 4; ++j)
        b4[j] = *reinterpret_cast<const float4*>(&sB[tx + 16 * j][kq * 4]);
#pragma unroll
      for (int i = 0; i < 4; ++i)
#pragma unroll
        for (int j = 0; j < 4; ++j) {
          acc[i][j] += a4[i].x * b4[j].x;
          acc[i][j] += a4[i].y * b4[j].y;
          acc[i][j] += a4[i].z * b4[j].z;
          acc[i][j] += a4[i].w * b4[j].w;
        }
    }
  }
#pragma unroll
  for (int j = 0; j < 4; ++j) {
    const int n = nt * 64 + tx + 16 * j;
    const float bb = b1[n] + b2[n];
    const int g = n >> 8, wvv = (n >> 4) & 15, u = n & 15;
#pragma unroll
    for (int i = 0; i < 4; ++i) {
      const int m = mt * 64 + ty + 16 * i;
      const int b = m >> 6, tt = m & 63;          // kCT == 64
      const int bblk = b >> 4, brow = b & 15;
      const size_t idx =
          ((((size_t)(bblk * 64 + tt) * 16 + wvv) * 4 + g) << 8) +
          (u << 4) + brow;
      P2[idx] = acc[i][j] + bb;
    }
  }
}

// out[b][n] = sum_k hlast[b][k] * fcw[n][k] + fcb[n]
__global__ __launch_bounds__(128) void fc_kernel(
    const float* __restrict__ hlast, const float* __restrict__ fcw,
    const float* __restrict__ fcb, float* __restrict__ out) {
  const int b = blockIdx.x;
  const int n = threadIdx.x;
  __shared__ float sh[kH];
  sh[n] = hlast[b * kH + n];
  sh[n + 128] = hlast[b * kH + n + 128];
  __syncthreads();
  if (n < kNC) {
    float a = fcb[n];
    const float* wrow = fcw + n * kH;
#pragma unroll 8
    for (int k = 0; k < kH; ++k) a += sh[k] * wrow[k];
    out[b * kNC + n] = a;
  }
}

}  // namespace

extern "C" void kernel_launch(void* const* d_in, const int* in_sizes, int n_in,
                              void* d_out, int out_size, void* d_ws, size_t ws_size,
                              hipStream_t stream) {
  (void)in_sizes; (void)n_in; (void)out_size; (void)ws_size;
  const float* x    = (const float*)d_in[0];
  const float* Wih0 = (const float*)d_in[1];
  const float* Whh0 = (const float*)d_in[2];
  const float* bih0 = (const float*)d_in[3];
  const float* bhh0 = (const float*)d_in[4];
  const float* Wih1 = (const float*)d_in[5];
  const float* Whh1 = (const float*)d_in[6];
  const float* bih1 = (const float*)d_in[7];
  const float* bhh1 = (const float*)d_in[8];
  const float* fcw  = (const float*)d_in[9];
  const float* fcb  = (const float*)d_in[10];
  float* out = (float*)d_out;

  // Workspace layout (~146 MB)
  char* base = (char*)d_ws;
  size_t off = 0;
  auto take = [&](size_t sz) { char* p = base + off; off += (sz + 255) & ~(size_t)255; return p; };
  const size_t szP  = (size_t)kB * kCT * kG * sizeof(float);   // 64 MB
  const size_t szH  = (size_t)kB * kCT * kH * sizeof(float);   // 16 MB
  const size_t szC  = (size_t)kB * kH * sizeof(float);         // 256 KB
  const size_t szHx = (size_t)2 * kB * kH * sizeof(unsigned short); // 256 KB
  const size_t szW  = (size_t)262144 * sizeof(unsigned short); // 512 KB
  const size_t szCnt = (size_t)16 * kCntSlot * sizeof(int);    // 36 KB

  float* P0  = (float*)take(szP);
  float* P1  = (float*)take(szP);
  float* H0  = (float*)take(szH);
  float* c0s = (float*)take(szC);
  float* c1s = (float*)take(szC);
  float* h1s = (float*)take(szC);
  unsigned short* hx0 = (unsigned short*)take(szHx);
  unsigned short* hx1 = (unsigned short*)take(szHx);
  unsigned short* Wpk0 = (unsigned short*)take(szW);
  unsigned short* Wpk1 = (unsigned short*)take(szW);
  int* cnt = (int*)take(szCnt);

  // Re-init exchange/counter state every call (graph replays included).
  hipMemsetAsync(cnt, 0, szCnt, stream);
  hipMemsetAsync(hx0, 0, szHx, stream);
  hipMemsetAsync(hx1, 0, szHx, stream);

  pack_whh_frag<<<dim3(1024), dim3(256), 0, stream>>>(Whh0, Wpk0);
  pack_whh_frag<<<dim3(1024), dim3(256), 0, stream>>>(Whh1, Wpk1);

  const dim3 ggrid(kG / 64, kB * kCT / 64);  // (16, 256)
  for (int ch = 0; ch < kNCh; ++ch) {
    const int first = (ch == 0) ? 1 : 0;
    gemm_xw<kIn><<<ggrid, dim3(256), 0, stream>>>(x, Wih0, bih0, bhh0, P0,
                                                  ch * kCT, kT);
    lstm_rec_coop<<<dim3(32), dim3(512), 0, stream>>>(
        P0, Wpk0, c0s, H0, nullptr, hx0, cnt + (ch * 2 + 0) * kCntSlot, first);
    gemm_xw<kH><<<ggrid, dim3(256), 0, stream>>>(H0, Wih1, bih1, bhh1, P1,
                                                 0, kCT);
    lstm_rec_coop<<<dim3(32), dim3(512), 0, stream>>>(
        P1, Wpk1, c1s, nullptr, h1s, hx1, cnt + (ch * 2 + 1) * kCntSlot, first);
  }
  fc_kernel<<<dim3(kB), dim3(128), 0, stream>>>(h1s, fcw, fcb, out);
}

// Round 7
// 5166.731 us; speedup vs baseline: 1.8476x; 1.1259x over previous
//
#include <hip/hip_runtime.h>
#include <math.h>

namespace {

constexpr int kB  = 256;   // batch
constexpr int kT  = 512;   // timesteps
constexpr int kIn = 128;   // layer0 input size
constexpr int kH  = 256;   // hidden
constexpr int kG  = 1024;  // 4*H
constexpr int kNC = 100;   // classes
constexpr int kCT = 64;    // timestep chunk
constexpr int kNCh = kT / kCT;
constexpr int kNS = 4;     // hidden slices (blocks per batch-group)
constexpr int kCntStep = 16;                      // ints per step flag (1 line)
constexpr int kCntRow  = (kCT + 1) * kCntStep;    // ints per bgroup
constexpr int kCntSlot = 8 * kCntRow;             // ints per dispatch slot

typedef __bf16 bf16x8 __attribute__((ext_vector_type(8)));
typedef float f32x4 __attribute__((ext_vector_type(4)));
static_assert(sizeof(bf16x8) == 16, "bf16x8 must be 4 VGPRs");

__device__ __forceinline__ float sigm(float x) {
  return __builtin_amdgcn_rcpf(1.0f + __expf(-x));
}
__device__ __forceinline__ float tanh_f(float x) {
  const float e = __expf(-2.0f * x);
  return (1.0f - e) * __builtin_amdgcn_rcpf(1.0f + e);
}
__device__ __forceinline__ unsigned short f2bf(float f) {
  return __builtin_bit_cast(unsigned short, (__bf16)f);
}

// Async global->LDS, 16B/lane, LLC-scope read (sc0|sc1 = aux 17): bypasses the
// (possibly stale) local L1/L2 so cross-XCD h exchange needs NO cache inv.
__device__ __forceinline__ void glds16_llc(const void* g, void* l) {
  __builtin_amdgcn_global_load_lds(
      (const __attribute__((address_space(1))) void*)g,
      (__attribute__((address_space(3))) void*)l, 16, 0, 17);
}

// bf16 store written through to LLC (no dirty line in local L2).
__device__ __forceinline__ void st_bf16_llc(unsigned short* p, unsigned short v) {
  asm volatile("global_store_short %0, %1, off sc0 sc1"
               :: "v"((unsigned long long)(uintptr_t)p), "v"(v) : "memory");
}

// ---------------------------------------------------------------------------
// Pack W_hh [4H][H] fp32 into bf16 MFMA B-fragment order:
//   flat = ((((wv16*4+g)*8)+kb)*64 + l)*8 + e
//   B[k][n] = Whh[n][k], n = g*256 + wv16*16 + (l&15), k = kb*32 + ((l>>4)&3)*8 + e
__global__ __launch_bounds__(256) void pack_whh_frag(
    const float* __restrict__ whh, unsigned short* __restrict__ wpk) {
  const int idx = blockIdx.x * 256 + threadIdx.x;   // 0..262143
  const int e  = idx & 7;
  const int l  = (idx >> 3) & 63;
  const int kb = (idx >> 9) & 7;
  const int g  = (idx >> 12) & 3;
  const int wv = idx >> 14;
  const int n = (g << 8) | (wv << 4) | (l & 15);
  const int k = (kb << 5) | (((l >> 4) & 3) << 3) | e;
  wpk[idx] = f2bf(whh[n * kH + k]);
}

// ---------------------------------------------------------------------------
// Hidden-partitioned LSTM recurrence. Grid: 32 blocks = 8 batch-groups(32 rows)
// x 4 hidden-slices(64 units). Block: 512 thr = 8 waves (2/SIMD). Wave (mi,ug)
// owns m-tile mi (16 rows) x 16 units x all 4 gates; W-slice pinned in VGPRs
// (asm "+v" prevents rematerialization). Per step, h slices are exchanged at
// LLC scope (sc0|sc1 stores + aux-17 global_load_lds) with one relaxed agent
// fetch_add per block and relaxed polls -- no buffer_inv/wbl2 in the loop.
__global__ __launch_bounds__(512, 2) void lstm_rec_coop(
    const float* __restrict__ P2,           // permuted projections (see gemm)
    const unsigned short* __restrict__ wpk, // packed bf16 B-fragments
    float* __restrict__ cstate,             // [kB][kH] fp32, block-exclusive
    float* __restrict__ Hout,               // [kB*kCT][kH] fp32 or null
    float* __restrict__ hlast,              // [kB][kH] fp32 or null
    unsigned short* __restrict__ hx,        // [2][kB][kH] bf16 exchange
    int* __restrict__ cnt,                  // [8][kCntRow], zeroed
    int first) {
  const int tid = threadIdx.x;
  const int wv = tid >> 6;          // 0..7
  const int l  = tid & 63;
  const int mi = wv >> 2;           // m-tile (16 rows)
  const int ug = wv & 3;            // unit group (16 units)
  const int bblk = blockIdx.x >> 2; // batch group (32 rows)
  const int hs   = blockIdx.x & 3;  // hidden slice (64 units)
  const int R0 = bblk << 5;
  const int wv16 = (hs << 2) | ug;                  // 0..15, matches pack/P2
  const int jj = (wv16 << 4) | (l & 15);            // owned hidden unit
  const int mg = (l >> 4) << 2;                     // row offset in m-tile
  const int rowb = R0 + (mi << 4) + mg;             // first of 4 owned rows

  __shared__ __align__(16) unsigned short albuf[2][8][512];  // 16KB A-frags

  int* cntb = cnt + bblk * kCntRow;
  unsigned short* hx0 = hx;
  unsigned short* hx1 = hx + (size_t)kB * kH;

  // ---- resident B-fragments: 4 gates x 8 kb = 128 VGPRs, pinned ----
  bf16x8 wr[4][8];
#pragma unroll
  for (int g = 0; g < 4; ++g)
#pragma unroll
    for (int kb = 0; kb < 8; ++kb) {
      wr[g][kb] = *reinterpret_cast<const bf16x8*>(
          wpk + (size_t)(((wv16 * 4 + g) * 8 + kb) * 64 + l) * 8);
      asm volatile("" : "+v"(wr[g][kb]));  // forbid rematerialization
    }

  // ---- c state ----
  f32x4 c4;
  float hnew[4];
  if (first) {
#pragma unroll
    for (int r = 0; r < 4; ++r) c4[r] = 0.f;
  } else {
#pragma unroll
    for (int r = 0; r < 4; ++r) c4[r] = cstate[(rowb + r) * kH + jj];
  }

  // ---- P2 base: step stride 16384 floats, gate stride 256 ----
  const float* __restrict__ Pb =
      P2 + ((size_t)((bblk * 2 + mi) * 64) * 16 + wv16) * 1024 +
      ((l & 15) << 4) + mg;
  f32x4 pfr[4];
#pragma unroll
  for (int g = 0; g < 4; ++g)
    pfr[g] = *reinterpret_cast<const f32x4*>(Pb + (g << 8));

  // ---- glds of A-frags: wave wv pulls frags (gmi, gkb..gkb+1) ----
  const int gmi = wv >> 2;
  const int gkb = (wv & 3) << 1;
  const int grow = R0 + (gmi << 4) + (l & 15);
  const int gcol0 = ((l >> 4) & 3) << 3;
#define ISSUE_GLDS(buf)                                                     \
  {                                                                         \
    _Pragma("unroll") for (int q = 0; q < 2; ++q) {                         \
      const int kb = gkb + q;                                               \
      glds16_llc((buf) + ((size_t)grow << 8) + (kb << 5) + gcol0,           \
                 &albuf[gmi][kb][0]);                                       \
    }                                                                       \
  }

  ISSUE_GLDS(hx0);  // step-0 input (zeros or previous chunk's h)

  for (int tt = 0; tt < kCT; ++tt) {
    __syncthreads();  // [A] drains glds: albuf valid for all waves

    f32x4 acc[4];
#pragma unroll
    for (int g = 0; g < 4; ++g) acc[g] = pfr[g];

    bf16x8 a_cur = *reinterpret_cast<const bf16x8*>(&albuf[mi][0][l * 8]);
#pragma unroll
    for (int kb = 0; kb < 8; ++kb) {
      bf16x8 a_nxt = a_cur;
      if (kb < 7)
        a_nxt = *reinterpret_cast<const bf16x8*>(&albuf[mi][kb + 1][l * 8]);
      acc[0] = __builtin_amdgcn_mfma_f32_16x16x32_bf16(a_cur, wr[0][kb], acc[0], 0, 0, 0);
      acc[1] = __builtin_amdgcn_mfma_f32_16x16x32_bf16(a_cur, wr[1][kb], acc[1], 0, 0, 0);
      acc[2] = __builtin_amdgcn_mfma_f32_16x16x32_bf16(a_cur, wr[2][kb], acc[2], 0, 0, 0);
      acc[3] = __builtin_amdgcn_mfma_f32_16x16x32_bf16(a_cur, wr[3][kb], acc[3], 0, 0, 0);
      a_cur = a_nxt;
    }

    // prefetch next step's P (latency hidden under act + exchange)
    if (tt + 1 < kCT) {
#pragma unroll
      for (int g = 0; g < 4; ++g)
        pfr[g] = *reinterpret_cast<const f32x4*>(
            Pb + (size_t)(tt + 1) * 16384 + (g << 8));
    }

    // ---- in-lane activation ----
#pragma unroll
    for (int r = 0; r < 4; ++r) {
      const float ig = sigm(acc[0][r]);
      const float fg = sigm(acc[1][r]);
      const float gg = tanh_f(acc[2][r]);
      const float og = sigm(acc[3][r]);
      const float cc = fg * c4[r] + ig * gg;
      c4[r] = cc;
      hnew[r] = og * tanh_f(cc);
    }

    // ---- publish h slice to the other exchange buffer (write-through LLC) --
    unsigned short* hw = ((tt + 1) & 1) ? hx1 : hx0;
#pragma unroll
    for (int r = 0; r < 4; ++r)
      st_bf16_llc(hw + ((size_t)(rowb + r) << 8) + jj, f2bf(hnew[r]));
    if (Hout) {
#pragma unroll
      for (int r = 0; r < 4; ++r)
        Hout[((size_t)(rowb + r) * kCT + tt) * kH + jj] = hnew[r];
    }
    if (hlast && tt == kCT - 1) {
#pragma unroll
      for (int r = 0; r < 4; ++r)
        hlast[(rowb + r) * kH + jj] = hnew[r];
    }

    __syncthreads();  // [B] every wave's stores are vmcnt-drained (at LLC)

    if (tt + 1 < kCT) {
      int* flag = cntb + (tt + 1) * kCntStep;
      if (tid == 0)
        __hip_atomic_fetch_add(flag, 1, __ATOMIC_RELAXED,
                               __HIP_MEMORY_SCOPE_AGENT);
      // all waves poll (lane-uniform relaxed agent load, no cache inv)
      while (__hip_atomic_load(flag, __ATOMIC_RELAXED,
                               __HIP_MEMORY_SCOPE_AGENT) < kNS)
        __builtin_amdgcn_s_sleep(1);
      unsigned short* hr = ((tt + 1) & 1) ? hx1 : hx0;
      ISSUE_GLDS(hr);
    }
  }
#undef ISSUE_GLDS

#pragma unroll
  for (int r = 0; r < 4; ++r) cstate[(rowb + r) * kH + jj] = c4[r];
}

// ---------------------------------------------------------------------------
// GEMM: acc[m][n] = sum_k X[xrow(m)][k] * W[n][k] + b1[n] + b2[n]
// Epilogue writes the recurrence-native P2 layout:
//   idx = (((bblk16*64+tt)*16 + wv16)*4 + g)*256 + u*16 + brow
template <int K>
__global__ __launch_bounds__(256) void gemm_xw(
    const float* __restrict__ X, const float* __restrict__ W,
    const float* __restrict__ b1, const float* __restrict__ b2,
    float* __restrict__ P2, int t0, int xT) {
  __shared__ float sA[64][20];
  __shared__ float sB[64][20];
  const int tid = threadIdx.x;
  const int tx = tid & 15;
  const int ty = tid >> 4;
  const int lm = tid >> 2;
  const int lk = (tid & 3) << 2;
  const int mt = blockIdx.y;
  const int nt = blockIdx.x;

  const int m_g = mt * 64 + lm;
  const int xrow = (m_g >> 6) * xT + t0 + (m_g & 63);
  const float* Arow = X + (size_t)xrow * K;
  const float* Brow = W + (size_t)(nt * 64 + lm) * K;

  float acc[4][4] = {};
  for (int kt = 0; kt < K; kt += 16) {
    const float4 av = *reinterpret_cast<const float4*>(Arow + kt + lk);
    const float4 bv = *reinterpret_cast<const float4*>(Brow + kt + lk);
    __syncthreads();
    *reinterpret_cast<float4*>(&sA[lm][lk]) = av;
    *reinterpret_cast<float4*>(&sB[lm][lk]) = bv;
    __syncthreads();
#pragma unroll
    for (int kq = 0; kq < 4; ++kq) {
      float4 a4[4], b4[4];
#pragma unroll
      for (int i = 0; i < 4; ++i)
        a4[i] = *reinterpret_cast<const float4*>(&sA[ty + 16 * i][kq * 4]);
#pragma unroll
      for (int j = 0; j < 4; ++j)
        b4[j] = *reinterpret_cast<const float4*>(&sB[tx + 16 * j][kq * 4]);
#pragma unroll
      for (int i = 0; i < 4; ++i)
#pragma unroll
        for (int j = 0; j < 4; ++j) {
          acc[i][j] += a4[i].x * b4[j].x;
          acc[i][j] += a4[i].y * b4[j].y;
          acc[i][j] += a4[i].z * b4[j].z;
          acc[i][j] += a4[i].w * b4[j].w;
        }
    }
  }
#pragma unroll
  for (int j = 0; j < 4; ++j) {
    const int n = nt * 64 + tx + 16 * j;
    const float bb = b1[n] + b2[n];
    const int g = n >> 8, wvv = (n >> 4) & 15, u = n & 15;
#pragma unroll
    for (int i = 0; i < 4; ++i) {
      const int m = mt * 64 + ty + 16 * i;
      const int b = m >> 6, tt = m & 63;          // kCT == 64
      const int bblk = b >> 4, brow = b & 15;
      const size_t idx =
          ((((size_t)(bblk * 64 + tt) * 16 + wvv) * 4 + g) << 8) +
          (u << 4) + brow;
      P2[idx] = acc[i][j] + bb;
    }
  }
}

// out[b][n] = sum_k hlast[b][k] * fcw[n][k] + fcb[n]
__global__ __launch_bounds__(128) void fc_kernel(
    const float* __restrict__ hlast, const float* __restrict__ fcw,
    const float* __restrict__ fcb, float* __restrict__ out) {
  const int b = blockIdx.x;
  const int n = threadIdx.x;
  __shared__ float sh[kH];
  sh[n] = hlast[b * kH + n];
  sh[n + 128] = hlast[b * kH + n + 128];
  __syncthreads();
  if (n < kNC) {
    float a = fcb[n];
    const float* wrow = fcw + n * kH;
#pragma unroll 8
    for (int k = 0; k < kH; ++k) a += sh[k] * wrow[k];
    out[b * kNC + n] = a;
  }
}

}  // namespace

extern "C" void kernel_launch(void* const* d_in, const int* in_sizes, int n_in,
                              void* d_out, int out_size, void* d_ws, size_t ws_size,
                              hipStream_t stream) {
  (void)in_sizes; (void)n_in; (void)out_size; (void)ws_size;
  const float* x    = (const float*)d_in[0];
  const float* Wih0 = (const float*)d_in[1];
  const float* Whh0 = (const float*)d_in[2];
  const float* bih0 = (const float*)d_in[3];
  const float* bhh0 = (const float*)d_in[4];
  const float* Wih1 = (const float*)d_in[5];
  const float* Whh1 = (const float*)d_in[6];
  const float* bih1 = (const float*)d_in[7];
  const float* bhh1 = (const float*)d_in[8];
  const float* fcw  = (const float*)d_in[9];
  const float* fcb  = (const float*)d_in[10];
  float* out = (float*)d_out;

  // Workspace layout (~146 MB)
  char* base = (char*)d_ws;
  size_t off = 0;
  auto take = [&](size_t sz) { char* p = base + off; off += (sz + 255) & ~(size_t)255; return p; };
  const size_t szP  = (size_t)kB * kCT * kG * sizeof(float);   // 64 MB
  const size_t szH  = (size_t)kB * kCT * kH * sizeof(float);   // 16 MB
  const size_t szC  = (size_t)kB * kH * sizeof(float);         // 256 KB
  const size_t szHx = (size_t)2 * kB * kH * sizeof(unsigned short); // 256 KB
  const size_t szW  = (size_t)262144 * sizeof(unsigned short); // 512 KB
  const size_t szCnt = (size_t)16 * kCntSlot * sizeof(int);    // ~532 KB

  float* P0  = (float*)take(szP);
  float* P1  = (float*)take(szP);
  float* H0  = (float*)take(szH);
  float* c0s = (float*)take(szC);
  float* c1s = (float*)take(szC);
  float* h1s = (float*)take(szC);
  unsigned short* hxA = (unsigned short*)take(szHx);
  unsigned short* hxB = (unsigned short*)take(szHx);
  unsigned short* Wpk0 = (unsigned short*)take(szW);
  unsigned short* Wpk1 = (unsigned short*)take(szW);
  int* cnt = (int*)take(szCnt);

  // Re-init exchange/counter state every call (graph replays included).
  hipMemsetAsync(cnt, 0, szCnt, stream);
  hipMemsetAsync(hxA, 0, szHx, stream);
  hipMemsetAsync(hxB, 0, szHx, stream);

  pack_whh_frag<<<dim3(1024), dim3(256), 0, stream>>>(Whh0, Wpk0);
  pack_whh_frag<<<dim3(1024), dim3(256), 0, stream>>>(Whh1, Wpk1);

  const dim3 ggrid(kG / 64, kB * kCT / 64);  // (16, 256)
  for (int ch = 0; ch < kNCh; ++ch) {
    const int first = (ch == 0) ? 1 : 0;
    gemm_xw<kIn><<<ggrid, dim3(256), 0, stream>>>(x, Wih0, bih0, bhh0, P0,
                                                  ch * kCT, kT);
    lstm_rec_coop<<<dim3(32), dim3(512), 0, stream>>>(
        P0, Wpk0, c0s, H0, nullptr, hxA, cnt + (ch * 2 + 0) * kCntSlot, first);
    gemm_xw<kH><<<ggrid, dim3(256), 0, stream>>>(H0, Wih1, bih1, bhh1, P1,
                                                 0, kCT);
    lstm_rec_coop<<<dim3(32), dim3(512), 0, stream>>>(
        P1, Wpk1, c1s, nullptr, h1s, hxB, cnt + (ch * 2 + 1) * kCntSlot, first);
  }
  fc_kernel<<<dim3(kB), dim3(128), 0, stream>>>(h1s, fcw, fcb, out);
}

// Round 8
// 2473.100 us; speedup vs baseline: 3.8600x; 2.0892x over previous
//
#include <hip/hip_runtime.h>
#include <math.h>

namespace {

constexpr int kB  = 256;   // batch
constexpr int kT  = 512;   // timesteps
constexpr int kIn = 128;   // layer0 input size
constexpr int kH  = 256;   // hidden
constexpr int kG  = 1024;  // 4*H
constexpr int kNC = 100;   // classes
constexpr int kCT = 64;    // timestep chunk
constexpr int kNCh = kT / kCT;
constexpr int kNS = 4;     // hidden slices per batch-group
constexpr int kCntStep = 32;                 // ints per step flag (128B)
constexpr int kCntRow  = 64 * kCntStep;      // ints per bgroup
constexpr int kCntSlot = 16 * kCntRow;       // ints per dispatch slot

typedef __bf16 bf16x8 __attribute__((ext_vector_type(8)));
typedef float f32x4 __attribute__((ext_vector_type(4)));
typedef unsigned short u16;
static_assert(sizeof(bf16x8) == 16, "bf16x8 must be 4 VGPRs");

__device__ __forceinline__ float sigm(float x) {
  return __builtin_amdgcn_rcpf(1.0f + __expf(-x));
}
__device__ __forceinline__ float tanh_f(float x) {
  const float e = __expf(-2.0f * x);
  return (1.0f - e) * __builtin_amdgcn_rcpf(1.0f + e);
}
__device__ __forceinline__ u16 f2bf(float f) {
  return __builtin_bit_cast(u16, (__bf16)f);
}
__device__ __forceinline__ float bf2f(u16 v) {
  return __builtin_bit_cast(float, ((unsigned)v) << 16);
}

// Async global->LDS, 16B/lane. Dest wave-uniform base; HW adds lane*16.
__device__ __forceinline__ void glds16(const void* g, void* l) {
  __builtin_amdgcn_global_load_lds(
      (const __attribute__((address_space(1))) void*)g,
      (__attribute__((address_space(3))) void*)l, 16, 0, 0);
}
// LLC-scope variant (sc0|sc1): bypasses possibly-stale local L1/L2.
__device__ __forceinline__ void glds16_llc(const void* g, void* l) {
  __builtin_amdgcn_global_load_lds(
      (const __attribute__((address_space(1))) void*)g,
      (__attribute__((address_space(3))) void*)l, 16, 0, 17);
}
// bf16 store written through to LLC (no dirty line in local L2).
__device__ __forceinline__ void st_bf16_llc(u16* p, u16 v) {
  asm volatile("global_store_short %0, %1, off sc0 sc1"
               :: "v"((unsigned long long)(uintptr_t)p), "v"(v) : "memory");
}

// ---------------------------------------------------------------------------
// Pack W_hh [4H][H] fp32 -> bf16 MFMA B-frags for the recurrence:
//   flat = (((wv16*4+g)*8+kb)*64 + l)*8 + e
//   value = Whh[n][k], n = g*256 + wv16*16 + (l&15), k = kb*32 + (l>>4)*8 + e
__global__ __launch_bounds__(256) void pack_whh_frag(
    const float* __restrict__ whh, u16* __restrict__ wpk) {
  const int idx = blockIdx.x * 256 + threadIdx.x;   // 0..262143
  const int e  = idx & 7;
  const int l  = (idx >> 3) & 63;
  const int kb = (idx >> 9) & 7;
  const int g  = (idx >> 12) & 3;
  const int wv = idx >> 14;
  const int n = (g << 8) | (wv << 4) | (l & 15);
  const int k = (kb << 5) | (((l >> 4) & 3) << 3) | e;
  wpk[idx] = f2bf(whh[n * kH + k]);
}

// Pack W_ih [kG][K] fp32 -> bf16 B-frags for the projection GEMM:
//   flat = ((n16*(K/32)+kb)*64 + l)*8 + e
//   value = W[n][k], n = n16*16 + (l&15), k = kb*32 + (l>>4)*8 + e
template <int K>
__global__ __launch_bounds__(256) void pack_wih_frag(
    const float* __restrict__ w, u16* __restrict__ wp) {
  constexpr int kbBits = (K == 128) ? 2 : 3;
  const int idx = blockIdx.x * 256 + threadIdx.x;
  const int e  = idx & 7;
  const int l  = (idx >> 3) & 63;
  const int kb = (idx >> 9) & ((K / 32) - 1);
  const int n16 = idx >> (9 + kbBits);
  const int n = (n16 << 4) | (l & 15);
  const int k = (kb << 5) | (((l >> 4) & 3) << 3) | e;
  wp[idx] = f2bf(w[n * K + k]);
}

// x [B][T][128] fp32 -> xbf [T][B][128] bf16 (t-major for the GEMM).
__global__ __launch_bounds__(256) void conv_x(
    const float* __restrict__ x, u16* __restrict__ xbf) {
  const int f4 = blockIdx.x * 256 + threadIdx.x;   // 0..4194303
  const int rowid = f4 >> 5;                       // b*512 + t
  const int c4 = f4 & 31;
  const int b = rowid >> 9, t = rowid & 511;
  const float4 v = reinterpret_cast<const float4*>(x)[f4];
  ushort4 o;
  o.x = f2bf(v.x); o.y = f2bf(v.y); o.z = f2bf(v.z); o.w = f2bf(v.w);
  reinterpret_cast<ushort4*>(xbf)[(t * 256 + b) * 32 + c4] = o;
}

// ---------------------------------------------------------------------------
// MFMA projection GEMM: P[m][n] = sum_k A[m][k]*W[n][k] + b1[n] + b2[n]
// A: t-major bf16 [tt][256 b][K]. Block tile: one (tt, 64 b) x 256 n (one g).
// Grid (4 g, 256 mt): mt -> tt = mt>>2, bq = mt&3. 4 waves; wave w owns
// n-frags w*4..w*4+3. Epilogue transposes via LDS and writes P2 bf16 in the
// recurrence-native layout [bblk][tt][wv16][g][u*16+brow].
template <int K>
__global__ __launch_bounds__(256, 4) void gemm_mfma(
    const u16* __restrict__ A, const u16* __restrict__ Bp,
    const float* __restrict__ b1, const float* __restrict__ b2,
    u16* __restrict__ P2) {
  constexpr int NKB = K / 32;
  const int g = blockIdx.x, mt = blockIdx.y;
  const int tt = mt >> 2, bq = mt & 3;
  const int tid = threadIdx.x, w = tid >> 6, l = tid & 63;

  __shared__ __align__(16) unsigned char smem[40960];
  u16* albuf = (u16*)smem;                 // [2][4][512]
  u16* bbuf  = (u16*)(smem + 8192);        // [2][16][512]
  u16* sout  = (u16*)smem;                 // [4][16][256] (epilogue reuse)

  const u16* Ab = A + ((size_t)(tt * 256 + bq * 64 + w * 16 + (l & 15))) * K +
                  ((l >> 4) & 3) * 8;
  const u16* Bb = Bp + ((size_t)((g * 16 + w * 4) * NKB) * 64 + l) * 8;

  float bb[4];
#pragma unroll
  for (int j = 0; j < 4; ++j) {
    const int n = g * 256 + (w * 4 + j) * 16 + (l & 15);
    bb[j] = b1[n] + b2[n];
  }

  f32x4 acc[4][4];
#pragma unroll
  for (int mf = 0; mf < 4; ++mf)
#pragma unroll
    for (int nf = 0; nf < 4; ++nf) acc[mf][nf] = f32x4{0.f, 0.f, 0.f, 0.f};

#define STAGE(kb, buf)                                                     \
  {                                                                        \
    glds16(Ab + (kb) * 32, albuf + ((buf) * 4 + w) * 512);                 \
    _Pragma("unroll") for (int j = 0; j < 4; ++j)                          \
        glds16(Bb + ((size_t)(j * NKB + (kb)) * 64) * 8,                   \
               bbuf + ((buf) * 16 + w * 4 + j) * 512);                     \
  }

  STAGE(0, 0);
#pragma unroll
  for (int kb = 0; kb < NKB; ++kb) {
    __syncthreads();  // drains glds: buf kb&1 valid
    if (kb + 1 < NKB) STAGE(kb + 1, (kb + 1) & 1);
    const int buf = kb & 1;
    bf16x8 af[4], bf[4];
#pragma unroll
    for (int mf = 0; mf < 4; ++mf)
      af[mf] = *reinterpret_cast<const bf16x8*>(albuf + (buf * 4 + mf) * 512 + l * 8);
#pragma unroll
    for (int nf = 0; nf < 4; ++nf)
      bf[nf] = *reinterpret_cast<const bf16x8*>(bbuf + (buf * 16 + w * 4 + nf) * 512 + l * 8);
#pragma unroll
    for (int mf = 0; mf < 4; ++mf)
#pragma unroll
      for (int nf = 0; nf < 4; ++nf)
        acc[mf][nf] = __builtin_amdgcn_mfma_f32_16x16x32_bf16(
            af[mf], bf[nf], acc[mf][nf], 0, 0, 0);
  }
#undef STAGE

  __syncthreads();  // all staging reads retired; smem reusable as sout
#pragma unroll
  for (int mf = 0; mf < 4; ++mf)
#pragma unroll
    for (int nf = 0; nf < 4; ++nf) {
      ushort4 p;
      p.x = f2bf(acc[mf][nf][0] + bb[nf]);
      p.y = f2bf(acc[mf][nf][1] + bb[nf]);
      p.z = f2bf(acc[mf][nf][2] + bb[nf]);
      p.w = f2bf(acc[mf][nf][3] + bb[nf]);
      *reinterpret_cast<ushort4*>(
          sout + (mf * 16 + w * 4 + nf) * 256 + (l & 15) * 16 + ((l >> 4) & 3) * 4) = p;
    }
  __syncthreads();
#pragma unroll
  for (int i = 0; i < 8; ++i) {
    const int chunk = i * 8 + (tid >> 5);  // 0..63
    const int mf = chunk >> 4, wc = chunk & 15;
    const size_t dst =
        ((((size_t)(bq * 4 + mf) * 64 + tt) * 16 + wc) * 4 + g) * 256 +
        (tid & 31) * 8;
    *reinterpret_cast<uint4*>(P2 + dst) =
        *reinterpret_cast<const uint4*>(sout + (mf * 16 + wc) * 256 + (tid & 31) * 8);
  }
}

// ---------------------------------------------------------------------------
// Hidden-partitioned LSTM recurrence. Grid: 64 blocks = 16 bgroups(16 rows)
// x 4 slices(64 units). Block: 256 thr = 4 waves. Wave ug owns 16 rows x
// 16 units x all 4 gates; W-slice pinned in regs. P2 is bf16. Exchange via
// LLC-scoped stores + relaxed agent counters (protocol from round 7).
__global__ __launch_bounds__(256, 1) void lstm_rec_coop(
    const u16* __restrict__ P2,            // bf16 permuted projections
    const u16* __restrict__ wpk,           // packed bf16 B-fragments
    float* __restrict__ cstate,            // [kB][kH] fp32, block-exclusive
    u16* __restrict__ HoutBf,              // [kCT][kB][kH] bf16 t-major or null
    float* __restrict__ hlast,             // [kB][kH] fp32 or null
    u16* __restrict__ hx,                  // [2][kB][kH] bf16 exchange
    int* __restrict__ cnt,                 // counters, zeroed
    int first) {
  const int tid = threadIdx.x;
  const int ug = tid >> 6;
  const int l  = tid & 63;
  const int bblk = blockIdx.x >> 2;   // 0..15
  const int hs   = blockIdx.x & 3;
  const int R0 = bblk << 4;
  const int wv16 = (hs << 2) | ug;
  const int jj = (wv16 << 4) | (l & 15);
  const int mg = ((l >> 4) & 3) << 2;
  const int rowb = R0 + mg;

  __shared__ __align__(16) u16 albuf[2][8][512];  // 16KB

  int* cntb = cnt + bblk * kCntRow;
  u16* hx0 = hx;
  u16* hx1 = hx + (size_t)kB * kH;

  // resident B-frags: 4 gates x 8 kb = 128 VGPRs, pinned
  bf16x8 wr[4][8];
#pragma unroll
  for (int g = 0; g < 4; ++g)
#pragma unroll
    for (int kb = 0; kb < 8; ++kb) {
      wr[g][kb] = *reinterpret_cast<const bf16x8*>(
          wpk + (size_t)(((wv16 * 4 + g) * 8 + kb) * 64 + l) * 8);
      asm volatile("" : "+v"(wr[g][kb]));
    }

  f32x4 c4;
  float hnew[4];
  if (first) {
#pragma unroll
    for (int r = 0; r < 4; ++r) c4[r] = 0.f;
  } else {
#pragma unroll
    for (int r = 0; r < 4; ++r) c4[r] = cstate[(rowb + r) * kH + jj];
  }

  // P2 (bf16) lane base: chunk (bblk,tt=0,wv16,g=0) + u*16 + brow
  const u16* __restrict__ Pb =
      P2 + ((size_t)bblk * 64 * 16 + wv16) * 1024 + ((l & 15) << 4) + mg;
  ushort4 pf[4];
#pragma unroll
  for (int g = 0; g < 4; ++g)
    pf[g] = *reinterpret_cast<const ushort4*>(Pb + (g << 8));

  // A-frag staging: wave ug pulls frags kb = ug*2, ug*2+1
  const int gkb = ug << 1;
#define ISSUE_GLDS(buf, bsel)                                               \
  {                                                                         \
    _Pragma("unroll") for (int q = 0; q < 2; ++q) {                         \
      const int kb = gkb + q;                                               \
      glds16_llc((buf) + ((size_t)(R0 + (l & 15))) * 256 + kb * 32 +        \
                     ((l >> 4) & 3) * 8,                                    \
                 &albuf[bsel][kb][0]);                                      \
    }                                                                       \
  }

  ISSUE_GLDS(hx0, 0);

  for (int tt = 0; tt < kCT; ++tt) {
    __syncthreads();  // [A] albuf[tt&1] + pf valid (vmcnt drain)

    f32x4 acc[4];
#pragma unroll
    for (int g = 0; g < 4; ++g) {
      acc[g][0] = bf2f(pf[g].x);
      acc[g][1] = bf2f(pf[g].y);
      acc[g][2] = bf2f(pf[g].z);
      acc[g][3] = bf2f(pf[g].w);
    }
    if (tt + 1 < kCT) {
#pragma unroll
      for (int g = 0; g < 4; ++g)
        pf[g] = *reinterpret_cast<const ushort4*>(
            Pb + (size_t)(tt + 1) * 16384 + (g << 8));
    }

    const u16* ab = &albuf[tt & 1][0][0];
#pragma unroll
    for (int kb = 0; kb < 8; ++kb) {
      const bf16x8 a = *reinterpret_cast<const bf16x8*>(ab + kb * 512 + l * 8);
      acc[0] = __builtin_amdgcn_mfma_f32_16x16x32_bf16(a, wr[0][kb], acc[0], 0, 0, 0);
      acc[1] = __builtin_amdgcn_mfma_f32_16x16x32_bf16(a, wr[1][kb], acc[1], 0, 0, 0);
      acc[2] = __builtin_amdgcn_mfma_f32_16x16x32_bf16(a, wr[2][kb], acc[2], 0, 0, 0);
      acc[3] = __builtin_amdgcn_mfma_f32_16x16x32_bf16(a, wr[3][kb], acc[3], 0, 0, 0);
    }

#pragma unroll
    for (int r = 0; r < 4; ++r) {
      const float ig = sigm(acc[0][r]);
      const float fg = sigm(acc[1][r]);
      const float gg = tanh_f(acc[2][r]);
      const float og = sigm(acc[3][r]);
      const float cc = fg * c4[r] + ig * gg;
      c4[r] = cc;
      hnew[r] = og * tanh_f(cc);
    }

    u16* hw = ((tt + 1) & 1) ? hx1 : hx0;
#pragma unroll
    for (int r = 0; r < 4; ++r)
      st_bf16_llc(hw + ((size_t)(rowb + r) << 8) + jj, f2bf(hnew[r]));
    if (HoutBf) {
#pragma unroll
      for (int r = 0; r < 4; ++r)
        HoutBf[((size_t)tt * 256 + rowb + r) * 256 + jj] = f2bf(hnew[r]);
    }
    if (hlast && tt == kCT - 1) {
#pragma unroll
      for (int r = 0; r < 4; ++r)
        hlast[(rowb + r) * kH + jj] = hnew[r];
    }

    __syncthreads();  // [B] stores vmcnt-drained (at LLC)

    if (tt + 1 < kCT) {
      int* flag = cntb + (tt + 1) * kCntStep;
      if (tid == 0)
        __hip_atomic_fetch_add(flag, 1, __ATOMIC_RELAXED,
                               __HIP_MEMORY_SCOPE_AGENT);
      while (__hip_atomic_load(flag, __ATOMIC_RELAXED,
                               __HIP_MEMORY_SCOPE_AGENT) < kNS)
        __builtin_amdgcn_s_sleep(1);
      const u16* hr = ((tt + 1) & 1) ? hx1 : hx0;
      ISSUE_GLDS(hr, (tt + 1) & 1);
    }
  }
#undef ISSUE_GLDS

#pragma unroll
  for (int r = 0; r < 4; ++r) cstate[(rowb + r) * kH + jj] = c4[r];
}

// out[b][n] = sum_k hlast[b][k] * fcw[n][k] + fcb[n]
__global__ __launch_bounds__(128) void fc_kernel(
    const float* __restrict__ hlast, const float* __restrict__ fcw,
    const float* __restrict__ fcb, float* __restrict__ out) {
  const int b = blockIdx.x;
  const int n = threadIdx.x;
  __shared__ float sh[kH];
  sh[n] = hlast[b * kH + n];
  sh[n + 128] = hlast[b * kH + n + 128];
  __syncthreads();
  if (n < kNC) {
    float a = fcb[n];
    const float* wrow = fcw + n * kH;
#pragma unroll 8
    for (int k = 0; k < kH; ++k) a += sh[k] * wrow[k];
    out[b * kNC + n] = a;
  }
}

}  // namespace

extern "C" void kernel_launch(void* const* d_in, const int* in_sizes, int n_in,
                              void* d_out, int out_size, void* d_ws, size_t ws_size,
                              hipStream_t stream) {
  (void)in_sizes; (void)n_in; (void)out_size; (void)ws_size;
  const float* x    = (const float*)d_in[0];
  const float* Wih0 = (const float*)d_in[1];
  const float* Whh0 = (const float*)d_in[2];
  const float* bih0 = (const float*)d_in[3];
  const float* bhh0 = (const float*)d_in[4];
  const float* Wih1 = (const float*)d_in[5];
  const float* Whh1 = (const float*)d_in[6];
  const float* bih1 = (const float*)d_in[7];
  const float* bhh1 = (const float*)d_in[8];
  const float* fcw  = (const float*)d_in[9];
  const float* fcb  = (const float*)d_in[10];
  float* out = (float*)d_out;

  char* base = (char*)d_ws;
  size_t off = 0;
  auto take = [&](size_t sz) { char* p = base + off; off += (sz + 255) & ~(size_t)255; return p; };
  const size_t szP2  = (size_t)kB * kCT * kG * 2;        // 32 MB bf16
  const size_t szXbf = (size_t)kT * kB * kIn * 2;        // 32 MB
  const size_t szH0  = (size_t)kCT * kB * kH * 2;        // 8 MB
  const size_t szC   = (size_t)kB * kH * 4;              // 256 KB
  const size_t szHx  = (size_t)2 * kB * kH * 2;          // 256 KB
  const size_t szWih0 = (size_t)64 * (kIn / 32) * 512 * 2;  // 256 KB
  const size_t szWih1 = (size_t)64 * (kH / 32) * 512 * 2;   // 512 KB
  const size_t szWhh = (size_t)262144 * 2;               // 512 KB
  const size_t szCnt = (size_t)16 * kCntSlot * 4;        // 2 MB

  u16* P2a  = (u16*)take(szP2);
  u16* P2b  = (u16*)take(szP2);
  u16* xbf  = (u16*)take(szXbf);
  u16* H0bf = (u16*)take(szH0);
  float* c0s = (float*)take(szC);
  float* c1s = (float*)take(szC);
  float* h1s = (float*)take(szC);
  u16* hxA = (u16*)take(szHx);
  u16* hxB = (u16*)take(szHx);
  u16* WpIh0 = (u16*)take(szWih0);
  u16* WpIh1 = (u16*)take(szWih1);
  u16* Wpk0 = (u16*)take(szWhh);
  u16* Wpk1 = (u16*)take(szWhh);
  int* cnt = (int*)take(szCnt);

  hipMemsetAsync(cnt, 0, szCnt, stream);
  hipMemsetAsync(hxA, 0, szHx, stream);
  hipMemsetAsync(hxB, 0, szHx, stream);

  conv_x<<<dim3(16384), dim3(256), 0, stream>>>(x, xbf);
  pack_wih_frag<kIn><<<dim3(512), dim3(256), 0, stream>>>(Wih0, WpIh0);
  pack_wih_frag<kH><<<dim3(1024), dim3(256), 0, stream>>>(Wih1, WpIh1);
  pack_whh_frag<<<dim3(1024), dim3(256), 0, stream>>>(Whh0, Wpk0);
  pack_whh_frag<<<dim3(1024), dim3(256), 0, stream>>>(Whh1, Wpk1);

  for (int ch = 0; ch < kNCh; ++ch) {
    const int first = (ch == 0) ? 1 : 0;
    gemm_mfma<kIn><<<dim3(4, 256), dim3(256), 0, stream>>>(
        xbf + (size_t)ch * kCT * kB * kIn, WpIh0, bih0, bhh0, P2a);
    lstm_rec_coop<<<dim3(64), dim3(256), 0, stream>>>(
        P2a, Wpk0, c0s, H0bf, nullptr, hxA, cnt + (ch * 2 + 0) * kCntSlot, first);
    gemm_mfma<kH><<<dim3(4, 256), dim3(256), 0, stream>>>(
        H0bf, WpIh1, bih1, bhh1, P2b);
    lstm_rec_coop<<<dim3(64), dim3(256), 0, stream>>>(
        P2b, Wpk1, c1s, nullptr, h1s, hxB, cnt + (ch * 2 + 1) * kCntSlot, first);
  }
  fc_kernel<<<dim3(kB), dim3(128), 0, stream>>>(h1s, fcw, fcb, out);
}

// Round 11
// 1858.858 us; speedup vs baseline: 5.1355x; 1.3304x over previous
//
#include <hip/hip_runtime.h>
#include <math.h>

namespace {

constexpr int kB  = 256;   // batch
constexpr int kT  = 512;   // timesteps
constexpr int kIn = 128;   // layer0 input size
constexpr int kH  = 256;   // hidden
constexpr int kG  = 1024;  // 4*H
constexpr int kNC = 100;   // classes
constexpr int kCT = 64;    // timestep chunk
constexpr int kNCh = kT / kCT;

typedef __bf16 bf16x8 __attribute__((ext_vector_type(8)));
typedef float f32x4 __attribute__((ext_vector_type(4)));
typedef int i32x4 __attribute__((ext_vector_type(4)));
typedef unsigned short u16;
static_assert(sizeof(bf16x8) == 16, "bf16x8 must be 4 VGPRs");

__device__ __forceinline__ float sigm(float x) {
  return __builtin_amdgcn_rcpf(1.0f + __expf(-x));
}
__device__ __forceinline__ float tanh_f(float x) {
  const float e = __expf(-2.0f * x);
  return (1.0f - e) * __builtin_amdgcn_rcpf(1.0f + e);
}
__device__ __forceinline__ u16 f2bf(float f) {
  return __builtin_bit_cast(u16, (__bf16)f);
}
__device__ __forceinline__ float bf2f(u16 v) {
  return __builtin_bit_cast(float, ((unsigned)v) << 16);
}

// Async global->LDS, 16B/lane. aux 0 = plain; 17 = sc0|sc1 (read at LLC).
__device__ __forceinline__ void glds16(const void* g, void* l) {
  __builtin_amdgcn_global_load_lds(
      (const __attribute__((address_space(1))) void*)g,
      (__attribute__((address_space(3))) void*)l, 16, 0, 0);
}
__device__ __forceinline__ void glds16_llc(const void* g, void* l) {
  __builtin_amdgcn_global_load_lds(
      (const __attribute__((address_space(1))) void*)g,
      (__attribute__((address_space(3))) void*)l, 16, 0, 17);
}
// Stores written through to LLC (visible device-wide after vmcnt drain).
__device__ __forceinline__ void st_bf16_llc(u16* p, u16 v) {
  asm volatile("global_store_short %0, %1, off sc0 sc1"
               :: "v"((unsigned long long)(uintptr_t)p), "v"(v) : "memory");
}
__device__ __forceinline__ void st_i32_llc(int* p, int v) {
  asm volatile("global_store_dword %0, %1, off sc0 sc1"
               :: "v"((unsigned long long)(uintptr_t)p), "v"(v) : "memory");
}
// Poll 16 ints (64B) at LLC scope with one waitcnt; returns min of the 16.
__device__ __forceinline__ int poll16_min(const int* p) {
  i32x4 a, b, c, d;
  asm volatile(
      "global_load_dwordx4 %0, %4, off sc0 sc1\n\t"
      "global_load_dwordx4 %1, %5, off sc0 sc1\n\t"
      "global_load_dwordx4 %2, %6, off sc0 sc1\n\t"
      "global_load_dwordx4 %3, %7, off sc0 sc1\n\t"
      "s_waitcnt vmcnt(0)"
      : "=v"(a), "=v"(b), "=v"(c), "=v"(d)
      : "v"((unsigned long long)(uintptr_t)p),
        "v"((unsigned long long)(uintptr_t)(p + 4)),
        "v"((unsigned long long)(uintptr_t)(p + 8)),
        "v"((unsigned long long)(uintptr_t)(p + 12))
      : "memory");
  int m = a.x;
  m = min(m, a.y); m = min(m, a.z); m = min(m, a.w);
  m = min(m, b.x); m = min(m, b.y); m = min(m, b.z); m = min(m, b.w);
  m = min(m, c.x); m = min(m, c.y); m = min(m, c.z); m = min(m, c.w);
  m = min(m, d.x); m = min(m, d.y); m = min(m, d.z); m = min(m, d.w);
  return m;
}

// ---------------------------------------------------------------------------
// Pack W_hh [4H][H] fp32 -> bf16 MFMA B-frags for the recurrence:
//   flat = (((wv16*4+g)*8+kb)*64 + l)*8 + e
//   value = Whh[n][k], n = g*256 + wv16*16 + (l&15), k = kb*32 + (l>>4)*8 + e
__global__ __launch_bounds__(256) void pack_whh_frag(
    const float* __restrict__ whh, u16* __restrict__ wpk) {
  const int idx = blockIdx.x * 256 + threadIdx.x;   // 0..262143
  const int e  = idx & 7;
  const int l  = (idx >> 3) & 63;
  const int kb = (idx >> 9) & 7;
  const int g  = (idx >> 12) & 3;
  const int wv = idx >> 14;
  const int n = (g << 8) | (wv << 4) | (l & 15);
  const int k = (kb << 5) | (((l >> 4) & 3) << 3) | e;
  wpk[idx] = f2bf(whh[n * kH + k]);
}

// Pack W_ih [kG][K] fp32 -> bf16 B-frags for the projection GEMM.
template <int K>
__global__ __launch_bounds__(256) void pack_wih_frag(
    const float* __restrict__ w, u16* __restrict__ wp) {
  constexpr int kbBits = (K == 128) ? 2 : 3;
  const int idx = blockIdx.x * 256 + threadIdx.x;
  const int e  = idx & 7;
  const int l  = (idx >> 3) & 63;
  const int kb = (idx >> 9) & ((K / 32) - 1);
  const int n16 = idx >> (9 + kbBits);
  const int n = (n16 << 4) | (l & 15);
  const int k = (kb << 5) | (((l >> 4) & 3) << 3) | e;
  wp[idx] = f2bf(w[n * K + k]);
}

// x [B][T][128] fp32 -> xbf [T][B][128] bf16 (t-major for the GEMM).
__global__ __launch_bounds__(256) void conv_x(
    const float* __restrict__ x, u16* __restrict__ xbf) {
  const int f4 = blockIdx.x * 256 + threadIdx.x;   // 0..4194303
  const int rowid = f4 >> 5;                       // b*512 + t
  const int c4 = f4 & 31;
  const int b = rowid >> 9, t = rowid & 511;
  const float4 v = reinterpret_cast<const float4*>(x)[f4];
  ushort4 o;
  o.x = f2bf(v.x); o.y = f2bf(v.y); o.z = f2bf(v.z); o.w = f2bf(v.w);
  reinterpret_cast<ushort4*>(xbf)[(t * 256 + b) * 32 + c4] = o;
}

// ---------------------------------------------------------------------------
// MFMA projection GEMM (unchanged from round 8, proven).
template <int K>
__global__ __launch_bounds__(256, 4) void gemm_mfma(
    const u16* __restrict__ A, const u16* __restrict__ Bp,
    const float* __restrict__ b1, const float* __restrict__ b2,
    u16* __restrict__ P2) {
  constexpr int NKB = K / 32;
  const int g = blockIdx.x, mt = blockIdx.y;
  const int tt = mt >> 2, bq = mt & 3;
  const int tid = threadIdx.x, w = tid >> 6, l = tid & 63;

  __shared__ __align__(16) unsigned char smem[40960];
  u16* albuf = (u16*)smem;                 // [2][4][512]
  u16* bbuf  = (u16*)(smem + 8192);        // [2][16][512]
  u16* sout  = (u16*)smem;                 // [4][16][256] (epilogue reuse)

  const u16* Ab = A + ((size_t)(tt * 256 + bq * 64 + w * 16 + (l & 15))) * K +
                  ((l >> 4) & 3) * 8;
  const u16* Bb = Bp + ((size_t)((g * 16 + w * 4) * NKB) * 64 + l) * 8;

  float bb[4];
#pragma unroll
  for (int j = 0; j < 4; ++j) {
    const int n = g * 256 + (w * 4 + j) * 16 + (l & 15);
    bb[j] = b1[n] + b2[n];
  }

  f32x4 acc[4][4];
#pragma unroll
  for (int mf = 0; mf < 4; ++mf)
#pragma unroll
    for (int nf = 0; nf < 4; ++nf) acc[mf][nf] = f32x4{0.f, 0.f, 0.f, 0.f};

#define STAGE(kb, buf)                                                     \
  {                                                                        \
    glds16(Ab + (kb) * 32, albuf + ((buf) * 4 + w) * 512);                 \
    _Pragma("unroll") for (int j = 0; j < 4; ++j)                          \
        glds16(Bb + ((size_t)(j * NKB + (kb)) * 64) * 8,                   \
               bbuf + ((buf) * 16 + w * 4 + j) * 512);                     \
  }

  STAGE(0, 0);
#pragma unroll
  for (int kb = 0; kb < NKB; ++kb) {
    __syncthreads();
    if (kb + 1 < NKB) STAGE(kb + 1, (kb + 1) & 1);
    const int buf = kb & 1;
    bf16x8 af[4], bf[4];
#pragma unroll
    for (int mf = 0; mf < 4; ++mf)
      af[mf] = *reinterpret_cast<const bf16x8*>(albuf + (buf * 4 + mf) * 512 + l * 8);
#pragma unroll
    for (int nf = 0; nf < 4; ++nf)
      bf[nf] = *reinterpret_cast<const bf16x8*>(bbuf + (buf * 16 + w * 4 + nf) * 512 + l * 8);
#pragma unroll
    for (int mf = 0; mf < 4; ++mf)
#pragma unroll
      for (int nf = 0; nf < 4; ++nf)
        acc[mf][nf] = __builtin_amdgcn_mfma_f32_16x16x32_bf16(
            af[mf], bf[nf], acc[mf][nf], 0, 0, 0);
  }
#undef STAGE

  __syncthreads();
#pragma unroll
  for (int mf = 0; mf < 4; ++mf)
#pragma unroll
    for (int nf = 0; nf < 4; ++nf) {
      ushort4 p;
      p.x = f2bf(acc[mf][nf][0] + bb[nf]);
      p.y = f2bf(acc[mf][nf][1] + bb[nf]);
      p.z = f2bf(acc[mf][nf][2] + bb[nf]);
      p.w = f2bf(acc[mf][nf][3] + bb[nf]);
      *reinterpret_cast<ushort4*>(
          sout + (mf * 16 + w * 4 + nf) * 256 + (l & 15) * 16 + ((l >> 4) & 3) * 4) = p;
    }
  __syncthreads();
#pragma unroll
  for (int i = 0; i < 8; ++i) {
    const int chunk = i * 8 + (tid >> 5);  // 0..63
    const int mf = chunk >> 4, wc = chunk & 15;
    const size_t dst =
        ((((size_t)(bq * 4 + mf) * 64 + tt) * 16 + wc) * 4 + g) * 256 +
        (tid & 31) * 8;
    *reinterpret_cast<uint4*>(P2 + dst) =
        *reinterpret_cast<const uint4*>(sout + (mf * 16 + wc) * 256 + (tid & 31) * 8);
  }
}

// ---------------------------------------------------------------------------
// Dual-role LSTM recurrence: 128 blocks; role = bid>>6 selects layer-0-chunk
// or layer-1-chunk work (independent). Per role: 64 blocks = 16 bgroups x 4
// hidden slices, LLC-scope exchange (R8-proven). New vs R8: per-WAVE done
// flags (wave drains own h stores with vmcnt(0), lane0 flags; readers poll
// all 16 wave-flags with 4 parallel dwordx4) and no second barrier.
__global__ __launch_bounds__(256, 1) void lstm_rec_dual(
    const u16* __restrict__ P2_0, const u16* __restrict__ wpk_0,
    float* __restrict__ cs_0, u16* __restrict__ Ho_0, float* __restrict__ hl_0,
    u16* __restrict__ hx_0, int* __restrict__ tg_0, int first_0,
    const u16* __restrict__ P2_1, const u16* __restrict__ wpk_1,
    float* __restrict__ cs_1, u16* __restrict__ Ho_1, float* __restrict__ hl_1,
    u16* __restrict__ hx_1, int* __restrict__ tg_1, int first_1) {
  const int role = blockIdx.x >> 6;
  const u16* P2  = role ? P2_1 : P2_0;
  if (!P2) return;
  const u16* wpk = role ? wpk_1 : wpk_0;
  float* cstate  = role ? cs_1 : cs_0;
  u16* HoutBf    = role ? Ho_1 : Ho_0;
  float* hlast   = role ? hl_1 : hl_0;
  u16* hx        = role ? hx_1 : hx_0;
  int* tags      = role ? tg_1 : tg_0;
  const int first = role ? first_1 : first_0;

  const int bid6 = blockIdx.x & 63;
  const int tid = threadIdx.x;
  const int ug = tid >> 6;            // wave in block (0..3)
  const int l  = tid & 63;
  const int bblk = bid6 & 15;         // batch group (16 rows)
  const int hs   = bid6 >> 4;         // hidden slice (64 units)
  const int R0 = bblk << 4;
  const int wv16 = (hs << 2) | ug;
  const int jj = (wv16 << 4) | (l & 15);
  const int mg = ((l >> 4) & 3) << 2;
  const int rowb = R0 + mg;

  __shared__ __align__(16) u16 albuf[2][8][512];  // 16KB

  int* tgb = tags + bblk * 1024;      // 64 steps x 16 wave-flags
  u16* hx0 = hx;
  u16* hx1 = hx + (size_t)kB * kH;

  // resident B-frags: 4 gates x 8 kb = 128 VGPRs, pinned
  bf16x8 wr[4][8];
#pragma unroll
  for (int g = 0; g < 4; ++g)
#pragma unroll
    for (int kb = 0; kb < 8; ++kb) {
      wr[g][kb] = *reinterpret_cast<const bf16x8*>(
          wpk + (size_t)(((wv16 * 4 + g) * 8 + kb) * 64 + l) * 8);
      asm volatile("" : "+v"(wr[g][kb]));
    }

  // ---- c state ----
  f32x4 c4;
  float hnew[4];
  if (first) {
#pragma unroll
    for (int r = 0; r < 4; ++r) c4[r] = 0.f;
  } else {
#pragma unroll
    for (int r = 0; r < 4; ++r) c4[r] = cstate[(rowb + r) * kH + jj];
  }

  // P2 (bf16) lane base
  const u16* __restrict__ Pb =
      P2 + ((size_t)bblk * 64 * 16 + wv16) * 1024 + ((l & 15) << 4) + mg;
  ushort4 pf[4];
#pragma unroll
  for (int g = 0; g < 4; ++g)
    pf[g] = *reinterpret_cast<const ushort4*>(Pb + (g << 8));

  const int gkb = ug << 1;
#define ISSUE_GLDS(buf, bsel)                                               \
  {                                                                         \
    _Pragma("unroll") for (int q = 0; q < 2; ++q) {                         \
      const int kb = gkb + q;                                               \
      glds16_llc((buf) + ((size_t)(R0 + (l & 15))) * 256 + kb * 32 +        \
                     ((l >> 4) & 3) * 8,                                    \
                 &albuf[bsel][kb][0]);                                      \
    }                                                                       \
  }

  ISSUE_GLDS(hx0, 0);

  for (int tt = 0; tt < kCT; ++tt) {
    __syncthreads();  // [A] albuf[tt&1] + all waves' glds drained

    f32x4 acc[4];
#pragma unroll
    for (int g = 0; g < 4; ++g) {
      acc[g][0] = bf2f(pf[g].x);
      acc[g][1] = bf2f(pf[g].y);
      acc[g][2] = bf2f(pf[g].z);
      acc[g][3] = bf2f(pf[g].w);
    }
    if (tt + 1 < kCT) {
#pragma unroll
      for (int g = 0; g < 4; ++g)
        pf[g] = *reinterpret_cast<const ushort4*>(
            Pb + (size_t)(tt + 1) * 16384 + (g << 8));
    }

    const u16* ab = &albuf[tt & 1][0][0];
#pragma unroll
    for (int kb = 0; kb < 8; ++kb) {
      const bf16x8 a = *reinterpret_cast<const bf16x8*>(ab + kb * 512 + l * 8);
      acc[0] = __builtin_amdgcn_mfma_f32_16x16x32_bf16(a, wr[0][kb], acc[0], 0, 0, 0);
      acc[1] = __builtin_amdgcn_mfma_f32_16x16x32_bf16(a, wr[1][kb], acc[1], 0, 0, 0);
      acc[2] = __builtin_amdgcn_mfma_f32_16x16x32_bf16(a, wr[2][kb], acc[2], 0, 0, 0);
      acc[3] = __builtin_amdgcn_mfma_f32_16x16x32_bf16(a, wr[3][kb], acc[3], 0, 0, 0);
    }

#pragma unroll
    for (int r = 0; r < 4; ++r) {
      const float ig = sigm(acc[0][r]);
      const float fg = sigm(acc[1][r]);
      const float gg = tanh_f(acc[2][r]);
      const float og = sigm(acc[3][r]);
      const float cc = fg * c4[r] + ig * gg;
      c4[r] = cc;
      hnew[r] = og * tanh_f(cc);
    }

    // publish h slice (sc0sc1 -> LLC)
    u16* hw = ((tt + 1) & 1) ? hx1 : hx0;
#pragma unroll
    for (int r = 0; r < 4; ++r)
      st_bf16_llc(hw + ((size_t)(rowb + r) << 8) + jj, f2bf(hnew[r]));

    if (tt + 1 < kCT) {
      const int want = tt + 1;
      // wave-local drain of the h stores, then this wave's done-flag
      asm volatile("s_waitcnt vmcnt(0)" ::: "memory");
      if (l == 0) st_i32_llc(tgb + want * 16 + (hs * 4 + ug), want);
      // non-critical outputs issued while others converge
      if (HoutBf) {
#pragma unroll
        for (int r = 0; r < 4; ++r)
          HoutBf[((size_t)tt * 256 + rowb + r) * 256 + jj] = f2bf(hnew[r]);
      }
      // poll all 16 wave-flags of this bgroup
      while (poll16_min(tgb + want * 16) < want)
        __builtin_amdgcn_s_sleep(1);
      const u16* hr = ((tt + 1) & 1) ? hx1 : hx0;
      ISSUE_GLDS(hr, (tt + 1) & 1);
    } else {
      if (HoutBf) {
#pragma unroll
        for (int r = 0; r < 4; ++r)
          HoutBf[((size_t)tt * 256 + rowb + r) * 256 + jj] = f2bf(hnew[r]);
      }
      if (hlast) {
#pragma unroll
        for (int r = 0; r < 4; ++r)
          hlast[(rowb + r) * kH + jj] = hnew[r];
      }
    }
  }
#undef ISSUE_GLDS

#pragma unroll
  for (int r = 0; r < 4; ++r) cstate[(rowb + r) * kH + jj] = c4[r];
}

// out[b][n] = sum_k hlast[b][k] * fcw[n][k] + fcb[n]
__global__ __launch_bounds__(128) void fc_kernel(
    const float* __restrict__ hlast, const float* __restrict__ fcw,
    const float* __restrict__ fcb, float* __restrict__ out) {
  const int b = blockIdx.x;
  const int n = threadIdx.x;
  __shared__ float sh[kH];
  sh[n] = hlast[b * kH + n];
  sh[n + 128] = hlast[b * kH + n + 128];
  __syncthreads();
  if (n < kNC) {
    float a = fcb[n];
    const float* wrow = fcw + n * kH;
#pragma unroll 8
    for (int k = 0; k < kH; ++k) a += sh[k] * wrow[k];
    out[b * kNC + n] = a;
  }
}

}  // namespace

extern "C" void kernel_launch(void* const* d_in, const int* in_sizes, int n_in,
                              void* d_out, int out_size, void* d_ws, size_t ws_size,
                              hipStream_t stream) {
  (void)in_sizes; (void)n_in; (void)out_size; (void)ws_size;
  const float* x    = (const float*)d_in[0];
  const float* Wih0 = (const float*)d_in[1];
  const float* Whh0 = (const float*)d_in[2];
  const float* bih0 = (const float*)d_in[3];
  const float* bhh0 = (const float*)d_in[4];
  const float* Wih1 = (const float*)d_in[5];
  const float* Whh1 = (const float*)d_in[6];
  const float* bih1 = (const float*)d_in[7];
  const float* bhh1 = (const float*)d_in[8];
  const float* fcw  = (const float*)d_in[9];
  const float* fcb  = (const float*)d_in[10];
  float* out = (float*)d_out;

  char* base = (char*)d_ws;
  size_t off = 0;
  auto take = [&](size_t sz) { char* p = base + off; off += (sz + 255) & ~(size_t)255; return p; };
  const size_t szP2   = (size_t)kB * kCT * kG * 2;        // 32 MB bf16
  const size_t szXbf  = (size_t)kT * kB * kIn * 2;        // 32 MB
  const size_t szH0   = (size_t)kCT * kB * kH * 2;        // 8 MB
  const size_t szC    = (size_t)kB * kH * 4;              // 256 KB
  const size_t szHx   = (size_t)2 * kB * kH * 2;          // 256 KB
  const size_t szWih0 = (size_t)64 * (kIn / 32) * 512 * 2;
  const size_t szWih1 = (size_t)64 * (kH / 32) * 512 * 2;
  const size_t szWhh  = (size_t)262144 * 2;
  const size_t szTags = (size_t)16 * 16 * 1024 * 4;       // 16 slots x 64KB

  u16* P2a  = (u16*)take(szP2);
  u16* P2b  = (u16*)take(szP2);
  u16* xbf  = (u16*)take(szXbf);
  u16* H0bf = (u16*)take(szH0);
  float* c0s = (float*)take(szC);
  float* c1s = (float*)take(szC);
  float* h1s = (float*)take(szC);
  u16* hxA = (u16*)take(szHx);
  u16* hxB = (u16*)take(szHx);
  u16* WpIh0 = (u16*)take(szWih0);
  u16* WpIh1 = (u16*)take(szWih1);
  u16* Wpk0 = (u16*)take(szWhh);
  u16* Wpk1 = (u16*)take(szWhh);
  int* tags = (int*)take(szTags);

  hipMemsetAsync(tags, 0, szTags, stream);
  hipMemsetAsync(hxA, 0, szHx, stream);
  hipMemsetAsync(hxB, 0, szHx, stream);

  conv_x<<<dim3(16384), dim3(256), 0, stream>>>(x, xbf);
  pack_wih_frag<kIn><<<dim3(512), dim3(256), 0, stream>>>(Wih0, WpIh0);
  pack_wih_frag<kH><<<dim3(1024), dim3(256), 0, stream>>>(Wih1, WpIh1);
  pack_whh_frag<<<dim3(1024), dim3(256), 0, stream>>>(Whh0, Wpk0);
  pack_whh_frag<<<dim3(1024), dim3(256), 0, stream>>>(Whh1, Wpk1);

  auto tslot = [&](int s) { return tags + (size_t)s * 16 * 1024; };

  // F(ch) = rec0(ch) || rec1(ch-1); slots: role0 -> 2*ch, role1 -> 2*(ch-1)+1
  gemm_mfma<kIn><<<dim3(4, 256), dim3(256), 0, stream>>>(
      xbf, WpIh0, bih0, bhh0, P2a);
  lstm_rec_dual<<<dim3(128), dim3(256), 0, stream>>>(
      P2a, Wpk0, c0s, H0bf, nullptr, hxA, tslot(0), 1,
      nullptr, nullptr, nullptr, nullptr, nullptr, nullptr, nullptr, 0);
  for (int ch = 1; ch < kNCh; ++ch) {
    gemm_mfma<kH><<<dim3(4, 256), dim3(256), 0, stream>>>(
        H0bf, WpIh1, bih1, bhh1, P2b);
    gemm_mfma<kIn><<<dim3(4, 256), dim3(256), 0, stream>>>(
        xbf + (size_t)ch * kCT * kB * kIn, WpIh0, bih0, bhh0, P2a);
    lstm_rec_dual<<<dim3(128), dim3(256), 0, stream>>>(
        P2a, Wpk0, c0s, H0bf, nullptr, hxA, tslot(2 * ch), (ch == 0) ? 1 : 0,
        P2b, Wpk1, c1s, nullptr, h1s, hxB, tslot(2 * (ch - 1) + 1),
        (ch == 1) ? 1 : 0);
  }
  gemm_mfma<kH><<<dim3(4, 256), dim3(256), 0, stream>>>(
      H0bf, WpIh1, bih1, bhh1, P2b);
  lstm_rec_dual<<<dim3(128), dim3(256), 0, stream>>>(
      nullptr, nullptr, nullptr, nullptr, nullptr, nullptr, nullptr, 0,
      P2b, Wpk1, c1s, nullptr, h1s, hxB, tslot(2 * (kNCh - 1) + 1), 0);
  fc_kernel<<<dim3(kB), dim3(128), 0, stream>>>(h1s, fcw, fcb, out);
}